// Round 8
// baseline (935.476 us; speedup 1.0000x reference)
//
#include <hip/hip_runtime.h>
#include <hip/hip_cooperative_groups.h>
#include <math.h>

namespace cg = cooperative_groups;

// ---------------- constants ----------------
#define NN 512
#define CSD 384
#define CZD 128
#define HD 8
#define CD 128
#define EPSV 1e-8f
#define INFV 100000.0f

// ---------------- ws float offsets ----------------
#define OFF_QN    ((size_t)0)
#define OFF_TR    ((size_t)2048)
#define OFF_ROWT  ((size_t)4096)
#define OFF_COLT  ((size_t)8192)
#define OFF_SB    ((size_t)12288)
#define OFF_QBUF  ((size_t)45056)
#define OFF_KV    ((size_t)569344)
#define OFF_QPR   ((size_t)1617920)
#define OFF_KPR   ((size_t)1716224)
#define OFF_VGR   ((size_t)1814528)
#define OFF_ZB    ((size_t)1880064)
#define OFF_A     ((size_t)3977216)
#define OFF_AMH   ((size_t)6074368)
#define OFF_AML   ((size_t)7122944)
#define OFF_UH    ((size_t)8171520)
#define OFF_UL    ((size_t)8499200)
#define OFF_VH    ((size_t)8826880)
#define OFF_VL    ((size_t)9154560)
#define OFF_VPH   ((size_t)9482240)
#define OFF_VPL   ((size_t)10006528)
#define OFF_OB0   ((size_t)10530816)
#define OFF_OB1   ((size_t)11055104)
#define OFF_OG0   ((size_t)11579392)
#define OFF_OG1   ((size_t)12103680)
#define OFF_FH    ((size_t)12627968)
#define OFF_FL    ((size_t)13266944)
#define OFF_PS    ((size_t)13905920)
#define OFF_SH    ((size_t)15085568)
#define OFF_SL    ((size_t)15183872)
#define OFF_WTH   ((size_t)15282176)
#define OFF_WTL   ((size_t)15970304)
#define OFF_WOH   ((size_t)16658432)
#define OFF_WOL   ((size_t)17137664)
#define OFF_AZP   ((size_t)17616896)

typedef __attribute__((ext_vector_type(4))) float f32x4;
typedef __attribute__((ext_vector_type(8))) short bf16x8;
typedef __attribute__((ext_vector_type(4))) short s16x4;
typedef unsigned short u16;

struct MegaP {
    const float *s, *g, *z, *T, *mask;
    const float *W_q, *b_q, *W_kv, *b_kv, *W_qp, *b_qp, *W_kp, *b_kp, *W_vg, *b_vg;
    const float *W_mg, *W_b, *b_b, *W_dz, *b_dz, *hw, *sw, *W_out, *b_out, *W_geo;
    float *ws;
    float *out;
};

__device__ __forceinline__ void qrot(const float q[4], const float* v, float* out) {
    float qw = q[0], qx = q[1], qy = q[2], qz = q[3];
    float ux = qy*v[2] - qz*v[1];
    float uy = qz*v[0] - qx*v[2];
    float uz = qx*v[1] - qy*v[0];
    float uux = qy*uz - qz*uy;
    float uuy = qz*ux - qx*uz;
    float uuz = qx*uy - qy*ux;
    out[0] = v[0] + 2.0f*(qw*ux + uux);
    out[1] = v[1] + 2.0f*(qw*uy + uuy);
    out[2] = v[2] + 2.0f*(qw*uz + uuz);
}

__device__ __forceinline__ void cvt2(float x, u16& h, u16& lo) {
    unsigned u = __float_as_uint(x);
    unsigned r = (u + 0x7FFFu + ((u >> 16) & 1u)) >> 16;
    h = (u16)r;
    float hf = __uint_as_float(r << 16);
    float lf = x - hf;
    unsigned u2 = __float_as_uint(lf);
    unsigned r2 = (u2 + 0x7FFFu + ((u2 >> 16) & 1u)) >> 16;
    lo = (u16)r2;
}
__device__ __forceinline__ float bf2f(u16 h) { return __uint_as_float((unsigned)h << 16); }

#define MFMA3(acc, avh, avl, bvh, bvl) \
    acc = __builtin_amdgcn_mfma_f32_16x16x32_bf16(avh, bvh, acc, 0, 0, 0); \
    acc = __builtin_amdgcn_mfma_f32_16x16x32_bf16(avh, bvl, acc, 0, 0, 0); \
    acc = __builtin_amdgcn_mfma_f32_16x16x32_bf16(avl, bvh, acc, 0, 0, 0);

// ================= phase bodies (verbatim from the verified 11-kernel version) ==========

__device__ void d_split(const MegaP& p, int task, int bx, int by, float* tile) {
    int t = threadIdx.x;
    u16* sh_ = (u16*)(p.ws + OFF_SH);
    u16* sl_ = (u16*)(p.ws + OFF_SL);
    u16* WTh = (u16*)(p.ws + OFF_WTH);
    u16* WTl = (u16*)(p.ws + OFF_WTL);
    u16* WOh = (u16*)(p.ws + OFF_WOH);
    u16* WOl = (u16*)(p.ws + OFF_WOL);
    if (task == 0) {
        const float* W; int ldn, sn0;
        if (bx < 16)      { W = p.W_q;  ldn = 1024; sn0 = bx*64; }
        else if (bx < 48) { W = p.W_kv; ldn = 2048; sn0 = (bx-16)*64; }
        else if (bx < 51) { W = p.W_qp; ldn = 192;  sn0 = (bx-48)*64; }
        else if (bx < 54) { W = p.W_kp; ldn = 192;  sn0 = (bx-51)*64; }
        else              { W = p.W_vg; ldn = 128;  sn0 = (bx-54)*64; }
        int k0 = by*64;
        #pragma unroll
        for (int lp = 0; lp < 4; lp++) {
            int kk = (t>>4) + lp*16, nn = (t&15)*4;
            float4 v = *(const float4*)(W + (size_t)(k0+kk)*ldn + sn0 + nn);
            tile[kk*68+nn]=v.x; tile[kk*68+nn+1]=v.y; tile[kk*68+nn+2]=v.z; tile[kk*68+nn+3]=v.w;
        }
        __syncthreads();
        #pragma unroll
        for (int lp = 0; lp < 4; lp++) {
            int nn = (t>>4) + lp*16, kk4 = (t&15)*4;
            s16x4 vh, vl;
            #pragma unroll
            for (int e = 0; e < 4; e++) {
                u16 h, lo; cvt2(tile[(kk4+e)*68 + nn], h, lo);
                vh[e] = (short)h; vl[e] = (short)lo;
            }
            size_t o = (size_t)(bx*64 + nn)*384 + by*64 + kk4;
            *(s16x4*)(WTh + o) = vh;
            *(s16x4*)(WTl + o) = vl;
        }
    } else if (task == 1) {
        int n0 = bx*64, k0 = by*64;
        #pragma unroll
        for (int lp = 0; lp < 4; lp++) {
            int kk = (t>>4) + lp*16, nn = (t&15)*4;
            float4 v = *(const float4*)(p.W_out + (size_t)(k0+kk)*384 + n0 + nn);
            tile[kk*68+nn]=v.x; tile[kk*68+nn+1]=v.y; tile[kk*68+nn+2]=v.z; tile[kk*68+nn+3]=v.w;
        }
        __syncthreads();
        #pragma unroll
        for (int lp = 0; lp < 4; lp++) {
            int nn = (t>>4) + lp*16, kk4 = (t&15)*4;
            s16x4 vh, vl;
            #pragma unroll
            for (int e = 0; e < 4; e++) {
                u16 h, lo; cvt2(tile[(kk4+e)*68 + nn], h, lo);
                vh[e] = (short)h; vl[e] = (short)lo;
            }
            size_t o = (size_t)(n0 + nn)*2496 + k0 + kk4;
            *(s16x4*)(WOh + o) = vh;
            *(s16x4*)(WOl + o) = vl;
        }
    } else {
        int m0 = bx*64, k0 = by*64;
        #pragma unroll
        for (int lp = 0; lp < 4; lp++) {
            int row = (t>>4) + lp*16, c4 = (t&15)*4;
            float4 v = *(const float4*)(p.s + (size_t)(m0+row)*384 + k0 + c4);
            s16x4 vh, vl;
            u16 h, lo;
            cvt2(v.x,h,lo); vh[0]=(short)h; vl[0]=(short)lo;
            cvt2(v.y,h,lo); vh[1]=(short)h; vl[1]=(short)lo;
            cvt2(v.z,h,lo); vh[2]=(short)h; vl[2]=(short)lo;
            cvt2(v.w,h,lo); vh[3]=(short)h; vl[3]=(short)lo;
            size_t o = (size_t)(m0+row)*384 + k0 + c4;
            *(s16x4*)(sh_ + o) = vh;
            *(s16x4*)(sl_ + o) = vl;
        }
    }
}

// zb v2: no LDS, W_b in registers, coalesced float4 reads, shfl-reduce
__device__ void d_zb(const MegaP& p, int i, int jq) {
    float* zb = p.ws + OFF_ZB;
    int j0 = jq*128;
    int t = threadIdx.x, w = t>>6, l = t&63;
    int jj = l>>5, c4 = (l&31)<<2;
    float wb[4][8];
    #pragma unroll
    for (int e=0;e<4;e++)
        #pragma unroll
        for (int h=0;h<8;h++) wb[e][h] = p.W_b[(c4+e)*8 + h];
    int jbase = j0 + w*32 + jj;
    const float* zp = p.z + ((size_t)i*512 + jbase)*128 + c4;
    for (int k = 0; k < 16; k++) {
        float4 v = *(const float4*)(zp + (size_t)k*256);
        float acc[8];
        #pragma unroll
        for (int h=0;h<8;h++)
            acc[h] = v.x*wb[0][h] + v.y*wb[1][h] + v.z*wb[2][h] + v.w*wb[3][h];
        #pragma unroll
        for (int h=0;h<8;h++) {
            #pragma unroll
            for (int m=16;m>0;m>>=1) acc[h] += __shfl_xor(acc[h], m);
        }
        if ((l&31) < 8) {
            int h = l&31;
            zb[((size_t)h*512 + i)*512 + jbase + k*2] = acc[h];
        }
    }
}

__device__ void d_proj(const MegaP& p, int bx, int ny) {
    const u16* sh_ = (const u16*)(p.ws + OFF_SH);
    const u16* sl_ = (const u16*)(p.ws + OFF_SL);
    const u16* WTh = (const u16*)(p.ws + OFF_WTH);
    const u16* WTl = (const u16*)(p.ws + OFF_WTL);
    const float* bias; float* C; int N, n0, base;
    if (ny < 16)      { bias=p.b_q;  C=p.ws+OFF_QBUF; N=1024; n0=ny*64;      base=0; }
    else if (ny < 48) { bias=p.b_kv; C=p.ws+OFF_KV;   N=2048; n0=(ny-16)*64; base=1024; }
    else if (ny < 51) { bias=p.b_qp; C=p.ws+OFF_QPR;  N=192;  n0=(ny-48)*64; base=3072; }
    else if (ny < 54) { bias=p.b_kp; C=p.ws+OFF_KPR;  N=192;  n0=(ny-51)*64; base=3264; }
    else              { bias=p.b_vg; C=p.ws+OFF_VGR;  N=128;  n0=(ny-54)*64; base=3456; }
    int m0 = bx*64;
    int t = threadIdx.x, w = t>>6, l = t&63, g = l>>4, li = l&15;
    const u16* Ah = sh_ + (size_t)(m0 + w*16 + li)*384 + g*8;
    const u16* Al = sl_ + (size_t)(m0 + w*16 + li)*384 + g*8;
    const u16* Bh0 = WTh + (size_t)(base + n0 + li)*384 + g*8;
    const u16* Bl0 = WTl + (size_t)(base + n0 + li)*384 + g*8;
    f32x4 acc[4] = {};
    for (int ks = 0; ks < 12; ks++) {
        bf16x8 avh = *(const bf16x8*)(Ah + ks*32);
        bf16x8 avl = *(const bf16x8*)(Al + ks*32);
        #pragma unroll
        for (int c = 0; c < 4; c++) {
            bf16x8 bvh = *(const bf16x8*)(Bh0 + (size_t)c*16*384 + ks*32);
            bf16x8 bvl = *(const bf16x8*)(Bl0 + (size_t)c*16*384 + ks*32);
            MFMA3(acc[c], avh, avl, bvh, bvl);
        }
    }
    #pragma unroll
    for (int c = 0; c < 4; c++) {
        int col = n0 + c*16 + li;
        float bb = bias[col];
        #pragma unroll
        for (int r = 0; r < 4; r++) {
            int row = m0 + w*16 + g*4 + r;
            C[(size_t)row*N + col] = acc[c][r] + bb;
        }
    }
}

// sg layout: s_q[0..3], s_t[4..7], s_qpts[8..199], s_kpts[200..391], s_Qsq[392..399], s_Ksq[400..407]
__device__ void d_geo(const MegaP& p, int n, float* sg) {
    float* s_q = sg; float* s_t = sg+4;
    float* s_qpts = sg+8; float* s_kpts = sg+200;
    float* s_Qsq = sg+392; float* s_Ksq = sg+400;
    const float* qpr = p.ws + OFF_QPR;
    const float* kpr = p.ws + OFF_KPR;
    const float* vgr = p.ws + OFF_VGR;
    const float* qbuf = p.ws + OFF_QBUF;
    const float* kvb = p.ws + OFF_KV;
    float* qn = p.ws + OFF_QN;
    float* tr = p.ws + OFF_TR;
    u16* Uh = (u16*)(p.ws + OFF_UH); u16* Ul = (u16*)(p.ws + OFF_UL);
    u16* Vh = (u16*)(p.ws + OFF_VH); u16* Vl = (u16*)(p.ws + OFF_VL);
    float* rowt = p.ws + OFF_ROWT; float* colt = p.ws + OFF_COLT;
    u16* Vph = (u16*)(p.ws + OFF_VPH); u16* Vpl = (u16*)(p.ws + OFF_VPL);
    int t = threadIdx.x;
    if (t == 0) {
        float q0=p.T[n*16+0], q1=p.T[n*16+1], q2=p.T[n*16+2], q3=p.T[n*16+3];
        float inv = 1.0f/sqrtf(q0*q0+q1*q1+q2*q2+q3*q3 + EPSV);
        float a0=q0*inv, a1=q1*inv, a2=q2*inv, a3=q3*inv;
        s_q[0]=a0; s_q[1]=a1; s_q[2]=a2; s_q[3]=a3;
        float u0=p.T[n*16+4], u1=p.T[n*16+5], u2=p.T[n*16+6];
        s_t[0]=u0; s_t[1]=u1; s_t[2]=u2;
        qn[n*4+0]=a0; qn[n*4+1]=a1; qn[n*4+2]=a2; qn[n*4+3]=a3;
        tr[n*3+0]=u0; tr[n*3+1]=u1; tr[n*3+2]=u2;
    }
    __syncthreads();
    float q[4]={s_q[0],s_q[1],s_q[2],s_q[3]};
    float t0=s_t[0], t1=s_t[1], t2=s_t[2];
    if (t < 128) {
        int m = t & 63;
        const float* raw = (t < 64) ? qpr : kpr;
        float pp[3] = {raw[n*192 + m], raw[n*192 + 64 + m], raw[n*192 + 128 + m]};
        float r[3]; qrot(q,pp,r);
        r[0]+=t0; r[1]+=t1; r[2]+=t2;
        float* dp = (t<64) ? s_qpts : s_kpts;
        dp[m*3+0]=r[0]; dp[m*3+1]=r[1]; dp[m*3+2]=r[2];
        float ss = r[0]*r[0]+r[1]*r[1]+r[2]*r[2];
        ss += __shfl_down(ss,4,8);
        ss += __shfl_down(ss,2,8);
        ss += __shfl_down(ss,1,8);
        if ((m&7)==0) ((t<64)?s_Qsq:s_Ksq)[m>>3] = ss;
    } else if (t < 192) {
        int o = t - 128;
        float in[16];
        #pragma unroll
        for (int c=0;c<16;c++){
            float acc=0.0f;
            #pragma unroll
            for (int i2=0;i2<8;i2++)  acc += p.W_mg[o*16+i2]*vgr[n*128+i2*16+c];
            #pragma unroll
            for (int i2=8;i2<16;i2++) acc += p.W_mg[o*16+i2]*p.g[n*128+(i2-8)*16+c];
            in[c]=acc;
        }
        float out[16];
        out[0]=in[0];
        qrot(q,in+1,out+1);
        qrot(q,in+4,out+4);
        float w=in[10];
        qrot(q,in+7,out+7);
        out[7]+=w*t0; out[8]+=w*t1; out[9]+=w*t2;
        #pragma unroll
        for (int c=10;c<16;c++) out[c]=in[c];
        int h=o>>3, pp2=o&7;
        size_t vb = ((size_t)(h*512+n))*256 + 128 + pp2*16;
        #pragma unroll
        for (int c=0;c<16;c++) {
            u16 hh, ll; cvt2(out[c], hh, ll);
            Vph[vb+c]=hh; Vpl[vb+c]=ll;
        }
    }
    #pragma unroll
    for (int l=0;l<4;l++){
        int f = t + l*256; int h = f>>7, c = f&127;
        u16 hh, ll; cvt2(kvb[(size_t)n*2048 + h*256 + 128 + c], hh, ll);
        Vph[((size_t)(h*512+n))*256 + c] = hh;
        Vpl[((size_t)(h*512+n))*256 + c] = ll;
    }
    __syncthreads();
    #pragma unroll
    for (int h = 0; h < 8; h++) {
        float hwv = log1pf(expf(p.hw[h])) * 0.09622504486493763f;
        if (t < 160) {
            float u, v;
            if (t < 128) {
                u = 0.05103103630798287f * qbuf[(size_t)n*1024 + h*128 + t];
                v = kvb[(size_t)n*2048 + h*256 + t];
            } else if (t < 152) {
                int d = t - 128;
                u = hwv * s_qpts[h*24 + d];
                v = s_kpts[h*24 + d];
            } else { u = 0.0f; v = 0.0f; }
            size_t o = ((size_t)h*512 + n)*160 + t;
            u16 hh, ll;
            cvt2(u, hh, ll); Uh[o]=hh; Ul[o]=ll;
            cvt2(v, hh, ll); Vh[o]=hh; Vl[o]=ll;
        }
        if (t == 160) rowt[h*512+n] = -0.5f*hwv*s_Qsq[h] + 0.5773502691896258f*p.b_b[h] - INFV;
        if (t == 161) colt[h*512+n] = -0.5f*hwv*s_Ksq[h];
    }
}

__device__ void d_scorefill(const MegaP& p, int bx, int by, int h) {
    const u16* Uh = (const u16*)(p.ws + OFF_UH);
    const u16* Ul = (const u16*)(p.ws + OFF_UL);
    const u16* Vh = (const u16*)(p.ws + OFF_VH);
    const u16* Vl = (const u16*)(p.ws + OFF_VL);
    const float* rowt = p.ws + OFF_ROWT;
    const float* colt = p.ws + OFF_COLT;
    const float* zb = p.ws + OFF_ZB;
    float* Am = p.ws + OFF_A;
    int m0 = bx*64, n0 = by*64;
    int t = threadIdx.x, w = t>>6, l = t&63, g = l>>4, li = l&15;
    const u16* Ah = Uh + ((size_t)h*512 + m0 + w*16 + li)*160 + g*8;
    const u16* Al = Ul + ((size_t)h*512 + m0 + w*16 + li)*160 + g*8;
    const u16* Bh0 = Vh + ((size_t)h*512 + n0 + li)*160 + g*8;
    const u16* Bl0 = Vl + ((size_t)h*512 + n0 + li)*160 + g*8;
    f32x4 acc[4] = {};
    #pragma unroll
    for (int ks = 0; ks < 5; ks++) {
        bf16x8 avh = *(const bf16x8*)(Ah + ks*32);
        bf16x8 avl = *(const bf16x8*)(Al + ks*32);
        #pragma unroll
        for (int c = 0; c < 4; c++) {
            bf16x8 bvh = *(const bf16x8*)(Bh0 + (size_t)c*16*160 + ks*32);
            bf16x8 bvl = *(const bf16x8*)(Bl0 + (size_t)c*16*160 + ks*32);
            MFMA3(acc[c], avh, avl, bvh, bvl);
        }
    }
    float swh = p.sw[h];
    #pragma unroll
    for (int c = 0; c < 4; c++) {
        int j = n0 + c*16 + li;
        float ct = colt[h*512 + j];
        float mj = p.mask[j];
        #pragma unroll
        for (int r = 0; r < 4; r++) {
            int i = m0 + w*16 + g*4 + r;
            float rt = rowt[h*512 + i];
            float mi = p.mask[i]*INFV;
            float zv = zb[((size_t)h*512 + i)*512 + j];
            Am[((size_t)h*512 + i)*512 + j] =
                (acc[c][r] + rt + ct + 0.5773502691896258f*zv + mi*mj)*swh;
        }
    }
}

// sm layout: red[0..7], sred(wv,c) = sm[8 + wv*8 + c]
__device__ void d_softmax(const MegaP& p, int row, float* smem) {
    float* red = smem;
    const float* Am = p.ws + OFF_A;
    u16* Amh = (u16*)(p.ws + OFF_AMH);
    u16* Aml = (u16*)(p.ws + OFF_AML);
    const float* qn = p.ws + OFF_QN;
    const float* tr = p.ws + OFF_TR;
    float* S = p.ws + OFF_SB;
    const float* pr = Am + (size_t)row*512;
    int t = threadIdx.x;
    float x0 = pr[t], x1 = pr[t+256];
    float m = fmaxf(x0, x1);
    #pragma unroll
    for (int o = 32; o > 0; o >>= 1) m = fmaxf(m, __shfl_xor(m, o));
    int wv = t >> 6, ln = t & 63;
    if (ln == 0) red[wv] = m;
    __syncthreads();
    m = fmaxf(fmaxf(red[0], red[1]), fmaxf(red[2], red[3]));
    float e0 = expf(x0 - m), e1 = expf(x1 - m);
    float sm = e0 + e1;
    #pragma unroll
    for (int o = 32; o > 0; o >>= 1) sm += __shfl_xor(sm, o);
    __syncthreads();
    if (ln == 0) red[4 + wv] = sm;
    __syncthreads();
    float inv = 1.0f / (red[4]+red[5]+red[6]+red[7]);
    float a0 = e0*inv, a1 = e1*inv;
    u16 hh, ll;
    cvt2(a0, hh, ll); Amh[(size_t)row*512 + t] = hh;     Aml[(size_t)row*512 + t] = ll;
    cvt2(a1, hh, ll); Amh[(size_t)row*512 + t+256] = hh; Aml[(size_t)row*512 + t+256] = ll;
    float4 q0 = *(const float4*)(qn + t*4);
    float4 q1 = *(const float4*)(qn + (t+256)*4);
    float acc[8];
    acc[0] = a0*q0.x + a1*q1.x;
    acc[1] = a0*q0.y + a1*q1.y;
    acc[2] = a0*q0.z + a1*q1.z;
    acc[3] = a0*q0.w + a1*q1.w;
    acc[4] = a0*tr[t*3+0] + a1*tr[(t+256)*3+0];
    acc[5] = a0*tr[t*3+1] + a1*tr[(t+256)*3+1];
    acc[6] = a0*tr[t*3+2] + a1*tr[(t+256)*3+2];
    acc[7] = a0 + a1;
    #pragma unroll
    for (int c = 0; c < 8; c++) {
        #pragma unroll
        for (int o = 32; o > 0; o >>= 1) acc[c] += __shfl_xor(acc[c], o);
    }
    if (ln == 0) {
        #pragma unroll
        for (int c = 0; c < 8; c++) smem[8 + wv*8 + c] = acc[c];
    }
    __syncthreads();
    if (t < 8) {
        int h = row >> 9, i = row & 511;
        S[i*64 + h*8 + t] = smem[8+t] + smem[16+t] + smem[24+t] + smem[32+t];
    }
}

// aT layout: aT[0..1535], part = aT+1536 (3072 floats)
__device__ void d_az(const MegaP& p, int i, int jq, float* aT) {
    float* part = aT + 1536;
    const u16* Amh = (const u16*)(p.ws + OFF_AMH);
    const u16* Aml = (const u16*)(p.ws + OFF_AML);
    float* azp = p.ws + OFF_AZP;
    int j0 = jq*128;
    int t = threadIdx.x;
    #pragma unroll
    for (int l2 = 0; l2 < 4; l2++) {
        int f = t + l2*256;
        int h = f >> 7, jl = f & 127;
        size_t idx = ((size_t)h*512 + i)*512 + j0 + jl;
        aT[jl*12 + h] = bf2f(Amh[idx]) + bf2f(Aml[idx]);
    }
    __syncthreads();
    int c2 = t & 63, sub = t >> 6;
    int jb = sub*32;
    float acc[8][2] = {};
    for (int jo = 0; jo < 32; jo++) {
        int j = jb + jo;
        float2 zv = *(const float2*)(p.z + ((size_t)i*512 + j0 + j)*128 + c2*2);
        float4 a0 = *(const float4*)(aT + j*12);
        float4 a1 = *(const float4*)(aT + j*12 + 4);
        acc[0][0] += a0.x*zv.x; acc[0][1] += a0.x*zv.y;
        acc[1][0] += a0.y*zv.x; acc[1][1] += a0.y*zv.y;
        acc[2][0] += a0.z*zv.x; acc[2][1] += a0.z*zv.y;
        acc[3][0] += a0.w*zv.x; acc[3][1] += a0.w*zv.y;
        acc[4][0] += a1.x*zv.x; acc[4][1] += a1.x*zv.y;
        acc[5][0] += a1.y*zv.x; acc[5][1] += a1.y*zv.y;
        acc[6][0] += a1.z*zv.x; acc[6][1] += a1.z*zv.y;
        acc[7][0] += a1.w*zv.x; acc[7][1] += a1.w*zv.y;
    }
    if (sub > 0) {
        #pragma unroll
        for (int h = 0; h < 8; h++) {
            part[(sub-1)*1024 + h*128 + c2*2 + 0] = acc[h][0];
            part[(sub-1)*1024 + h*128 + c2*2 + 1] = acc[h][1];
        }
    }
    __syncthreads();
    if (sub == 0) {
        float* dst = azp + ((size_t)jq*512 + i)*1024;
        #pragma unroll
        for (int h = 0; h < 8; h++) {
            #pragma unroll
            for (int d = 0; d < 2; d++) {
                dst[h*128 + c2*2 + d] = acc[h][d] + part[h*128 + c2*2 + d]
                          + part[1024 + h*128 + c2*2 + d] + part[2048 + h*128 + c2*2 + d];
            }
        }
    }
}

// sB layout (u16): sBh(buf,idx)=sB[buf*3072+idx], sBl(buf,idx)=sB[6144+buf*3072+idx]
__device__ void d_apply(const MegaP& p, int bx, int by, int bz, u16* sB) {
    const u16* Amh = (const u16*)(p.ws + OFF_AMH);
    const u16* Aml = (const u16*)(p.ws + OFF_AML);
    const u16* Vph = (const u16*)(p.ws + OFF_VPH);
    const u16* Vpl = (const u16*)(p.ws + OFF_VPL);
    float* ob0 = p.ws + OFF_OB0; float* ob1 = p.ws + OFF_OB1;
    float* og0 = p.ws + OFF_OG0; float* og1 = p.ws + OFF_OG1;
    int m0 = bx*64, n0 = by*64;
    int h = bz & 7, js = bz >> 3;
    int t = threadIdx.x, w = t>>6, l = t&63, g = l>>4, li = l&15;
    int jl = t>>3, c8 = (t&7)*8;
    int jsw = jl ^ (((c8>>3)&3)<<3);
    const u16* Ah = Amh + ((size_t)h*512 + m0 + w*16 + li)*512 + js*256 + g*8;
    const u16* Al = Aml + ((size_t)h*512 + m0 + w*16 + li)*512 + js*256 + g*8;
    f32x4 acc[4] = {};
    {
        const u16* srcH = Vph + ((size_t)h*512 + js*256 + jl)*256 + n0 + c8;
        const u16* srcL = Vpl + ((size_t)h*512 + js*256 + jl)*256 + n0 + c8;
        bf16x8 vh = *(const bf16x8*)srcH;
        bf16x8 vl = *(const bf16x8*)srcL;
        #pragma unroll
        for (int e = 0; e < 8; e++) {
            sB[(c8+e)*48 + jsw] = (u16)vh[e];
            sB[6144 + (c8+e)*48 + jsw] = (u16)vl[e];
        }
    }
    __syncthreads();
    for (int kc = 0; kc < 8; kc++) {
        int cur = kc & 1;
        if (kc + 1 < 8) {
            int koff = js*256 + (kc+1)*32;
            const u16* srcH = Vph + ((size_t)h*512 + koff + jl)*256 + n0 + c8;
            const u16* srcL = Vpl + ((size_t)h*512 + koff + jl)*256 + n0 + c8;
            bf16x8 vh = *(const bf16x8*)srcH;
            bf16x8 vl = *(const bf16x8*)srcL;
            #pragma unroll
            for (int e = 0; e < 8; e++) {
                sB[(cur^1)*3072 + (c8+e)*48 + jsw] = (u16)vh[e];
                sB[6144 + (cur^1)*3072 + (c8+e)*48 + jsw] = (u16)vl[e];
            }
        }
        bf16x8 avh = *(const bf16x8*)(Ah + kc*32);
        bf16x8 avl = *(const bf16x8*)(Al + kc*32);
        #pragma unroll
        for (int c = 0; c < 4; c++) {
            int col = c*16 + li;
            int gp = g ^ ((col>>3)&3);
            bf16x8 bvh = *(const bf16x8*)(&sB[cur*3072 + col*48 + gp*8]);
            bf16x8 bvl = *(const bf16x8*)(&sB[6144 + cur*3072 + col*48 + gp*8]);
            MFMA3(acc[c], avh, avl, bvh, bvl);
        }
        __syncthreads();
    }
    float* obuf = js ? ob1 : ob0;
    float* og   = js ? og1 : og0;
    #pragma unroll
    for (int c = 0; c < 4; c++) {
        int col = n0 + c*16 + li;
        float* base = (col < 128) ? (obuf + h*128 + col) : (og + h*128 + col - 128);
        #pragma unroll
        for (int r = 0; r < 4; r++) {
            int i = m0 + w*16 + g*4 + r;
            base[(size_t)i*1024] = acc[c][r];
        }
    }
}

// s_az layout: s_az[0..1023], s_og = s_az + 1024
__device__ void d_azfin(const MegaP& p, int i, float* s_az) {
    float* s_og = s_az + 1024;
    const float* azp = p.ws + OFF_AZP;
    const float* ob0 = p.ws + OFF_OB0; const float* ob1 = p.ws + OFF_OB1;
    const float* og0 = p.ws + OFF_OG0; const float* og1 = p.ws + OFF_OG1;
    const float* S = p.ws + OFF_SB;
    const float* qn = p.ws + OFF_QN;
    const float* tr = p.ws + OFF_TR;
    u16* fh = (u16*)(p.ws + OFF_FH);
    u16* fl = (u16*)(p.ws + OFF_FL);
    float* outg = p.out + (size_t)NN*CSD;
    int t = threadIdx.x;
    #pragma unroll
    for (int l2 = 0; l2 < 4; l2++) {
        int c = t + l2*256;
        s_az[c] = azp[((size_t)0*512 + i)*1024 + c] + azp[((size_t)1*512 + i)*1024 + c]
                + azp[((size_t)2*512 + i)*1024 + c] + azp[((size_t)3*512 + i)*1024 + c];
    }
    __syncthreads();
    size_t fb = (size_t)i*2496;
    u16 hh, ll;
    #pragma unroll
    for (int l = 0; l < 4; l++) {
        int ff = t + l*256; int h = ff>>7, c = ff&127;
        float v = ob0[(size_t)i*1024 + h*128 + c] + ob1[(size_t)i*1024 + h*128 + c];
        cvt2(v, hh, ll); fh[fb + h*312 + 32 + c] = hh; fl[fb + h*312 + 32 + c] = ll;
    }
    {
        int h = t >> 5, cdz = t & 31;
        float a2 = p.b_dz[cdz];
        #pragma unroll 4
        for (int zc = 0; zc < 128; zc++) a2 += s_az[h*128 + zc]*p.W_dz[zc*32 + cdz];
        cvt2(a2, hh, ll); fh[fb + h*312 + cdz] = hh; fl[fb + h*312 + cdz] = ll;
    }
    float qc0=qn[i*4], qc1=-qn[i*4+1], qc2=-qn[i*4+2], qc3=-qn[i*4+3];
    float t0=tr[i*3], t1=tr[i*3+1], t2=tr[i*3+2];
    if (t < 64) {
        int h = t >> 3, pp = t & 7;
        const float* a0 = og0 + (size_t)i*1024 + h*128 + pp*16;
        const float* a1 = og1 + (size_t)i*1024 + h*128 + pp*16;
        float in[16];
        #pragma unroll
        for (int c=0;c<16;c++) in[c]=a0[c]+a1[c];
        float qc[4]={qc0,qc1,qc2,qc3};
        float out[16];
        out[0]=in[0];
        qrot(qc,in+1,out+1);
        qrot(qc,in+4,out+4);
        float w=in[10];
        float tmp[3]={in[7]-w*t0, in[8]-w*t1, in[9]-w*t2};
        qrot(qc,tmp,out+7);
        #pragma unroll
        for (int c2x=10;c2x<16;c2x++) out[c2x]=in[c2x];
        float n1=EPSV, n2=EPSV;
        #pragma unroll
        for (int c2x=0;c2x<10;c2x++) n1 += out[c2x]*out[c2x];
        #pragma unroll
        for (int c2x=10;c2x<16;c2x++) n2 += out[c2x]*out[c2x];
        n1=sqrtf(n1); n2=sqrtf(n2);
        #pragma unroll
        for (int c2x=0;c2x<16;c2x++){
            cvt2(out[c2x], hh, ll);
            fh[fb + h*312+168+pp*16+c2x] = hh; fl[fb + h*312+168+pp*16+c2x] = ll;
            s_og[t*16+c2x]=out[c2x];
        }
        cvt2(n1, hh, ll); fh[fb + h*312+296+pp*2]   = hh; fl[fb + h*312+296+pp*2]   = ll;
        cvt2(n2, hh, ll); fh[fb + h*312+296+pp*2+1] = hh; fl[fb + h*312+296+pp*2+1] = ll;
    } else if (t < 72) {
        int h = t - 64;
        const float* Sr = S + i*64 + h*8;
        float b0=Sr[0], b1=Sr[1], b2=Sr[2], b3=Sr[3];
        float o0 = qc0*b0 - qc1*b1 - qc2*b2 - qc3*b3;
        float o1 = qc0*b1 + qc1*b0 + qc2*b3 - qc3*b2;
        float o2 = qc0*b2 - qc1*b3 + qc2*b0 + qc3*b1;
        float o3 = qc0*b3 + qc1*b2 - qc2*b1 + qc3*b0;
        float A = Sr[7];
        float v[3]={Sr[4]-A*t0, Sr[5]-A*t1, Sr[6]-A*t2};
        float qc[4]={qc0,qc1,qc2,qc3};
        float r[3]; qrot(qc,v,r);
        cvt2(o0,hh,ll);  fh[fb+h*312+160]=hh; fl[fb+h*312+160]=ll;
        cvt2(o1,hh,ll);  fh[fb+h*312+161]=hh; fl[fb+h*312+161]=ll;
        cvt2(o2,hh,ll);  fh[fb+h*312+162]=hh; fl[fb+h*312+162]=ll;
        cvt2(o3,hh,ll);  fh[fb+h*312+163]=hh; fl[fb+h*312+163]=ll;
        cvt2(r[0],hh,ll);fh[fb+h*312+164]=hh; fl[fb+h*312+164]=ll;
        cvt2(r[1],hh,ll);fh[fb+h*312+165]=hh; fl[fb+h*312+165]=ll;
        cvt2(r[2],hh,ll);fh[fb+h*312+166]=hh; fl[fb+h*312+166]=ll;
        fh[fb+h*312+167]=0; fl[fb+h*312+167]=0;
    }
    __syncthreads();
    if (t < 128) {
        int o = (t>>4) & 7, c = t & 15;
        float a3 = 0.0f;
        #pragma unroll 4
        for (int i2=0;i2<64;i2++) a3 += p.W_geo[o*64+i2]*s_og[i2*16+c];
        outg[(size_t)i*128 + o*16 + c] = a3;
    }
}

__device__ void d_sout(const MegaP& p, int bx, int by, int kz) {
    const u16* fh = (const u16*)(p.ws + OFF_FH);
    const u16* fl = (const u16*)(p.ws + OFF_FL);
    const u16* WOh = (const u16*)(p.ws + OFF_WOH);
    const u16* WOl = (const u16*)(p.ws + OFF_WOL);
    float* Ps = p.ws + OFF_PS;
    int m0 = bx*64, n0 = by*64;
    int t = threadIdx.x, w = t>>6, l = t&63, g = l>>4, li = l&15;
    const u16* Ah = fh + (size_t)(m0 + w*16 + li)*2496 + kz*416 + g*8;
    const u16* Al = fl + (size_t)(m0 + w*16 + li)*2496 + kz*416 + g*8;
    const u16* Bh0 = WOh + (size_t)(n0 + li)*2496 + kz*416 + g*8;
    const u16* Bl0 = WOl + (size_t)(n0 + li)*2496 + kz*416 + g*8;
    f32x4 acc[4] = {};
    for (int ks = 0; ks < 13; ks++) {
        bf16x8 avh = *(const bf16x8*)(Ah + ks*32);
        bf16x8 avl = *(const bf16x8*)(Al + ks*32);
        #pragma unroll
        for (int c = 0; c < 4; c++) {
            bf16x8 bvh = *(const bf16x8*)(Bh0 + (size_t)c*16*2496 + ks*32);
            bf16x8 bvl = *(const bf16x8*)(Bl0 + (size_t)c*16*2496 + ks*32);
            MFMA3(acc[c], avh, avl, bvh, bvl);
        }
    }
    float* slab = Ps + (size_t)kz*512*384;
    #pragma unroll
    for (int c = 0; c < 4; c++) {
        int col = n0 + c*16 + li;
        #pragma unroll
        for (int r = 0; r < 4; r++) {
            int row = m0 + w*16 + g*4 + r;
            slab[(size_t)row*CSD + col] = acc[c][r];
        }
    }
}

__device__ void d_red(const MegaP& p, int u) {
    const float* Ps = p.ws + OFF_PS;
    int idx = (u*256 + threadIdx.x)*4;
    float4 s = *(const float4*)(p.b_out + (idx % 384));
    #pragma unroll
    for (int kz = 0; kz < 6; kz++) {
        float4 pp = *(const float4*)(Ps + (size_t)kz*196608 + idx);
        s.x += pp.x; s.y += pp.y; s.z += pp.z; s.w += pp.w;
    }
    *(float4*)(p.out + idx) = s;
}

// ================= cooperative mega-kernel ==========

__global__ __launch_bounds__(256) void k_mega(MegaP p) {
    __shared__ __align__(16) unsigned char smraw[24576];
    float* smf = (float*)smraw;
    u16*   smu = (u16*)smraw;
    cg::grid_group gg = cg::this_grid();
    int bid = blockIdx.x;
    // P0: split (618 vbs) + zb (2048 vbs) -- both dependency-free
    for (int vb = bid; vb < 2666; vb += 512) {
        __syncthreads();
        if (vb < 336)      d_split(p, 0, vb % 56, vb / 56, smf);
        else if (vb < 570) { int u = vb - 336; d_split(p, 1, u % 6, u / 6, smf); }
        else if (vb < 618) { int u = vb - 570; d_split(p, 2, u % 8, u / 8, smf); }
        else               { int u = vb - 618; d_zb(p, u >> 2, u & 3); }
    }
    gg.sync();
    // P1: projections (448 vbs)
    for (int vb = bid; vb < 448; vb += 512)
        d_proj(p, vb & 7, vb >> 3);
    gg.sync();
    // P2: geo (512 vbs)
    {
        __syncthreads();
        d_geo(p, bid, smf);
    }
    gg.sync();
    // P3: scorefill (512 vbs)
    d_scorefill(p, bid & 7, (bid >> 3) & 7, bid >> 6);
    gg.sync();
    // P4: softmax (4096 vbs)
    for (int vb = bid; vb < 4096; vb += 512) {
        __syncthreads();
        d_softmax(p, vb, smf);
    }
    gg.sync();
    // P5: az (2048) + apply (512)
    for (int vb = bid; vb < 2560; vb += 512) {
        __syncthreads();
        if (vb < 2048) d_az(p, vb >> 2, vb & 3, smf);
        else { int u = vb - 2048; d_apply(p, u & 7, (u >> 3) & 3, u >> 5, smu); }
    }
    gg.sync();
    // P6: azfin (512 vbs)
    {
        __syncthreads();
        d_azfin(p, bid, smf);
    }
    gg.sync();
    // P7: sout (288 vbs)
    for (int vb = bid; vb < 288; vb += 512)
        d_sout(p, vb % 8, (vb / 8) % 6, vb / 48);
    gg.sync();
    // P8: reduce (192 vbs)
    for (int vb = bid; vb < 192; vb += 512)
        d_red(p, vb);
}

// ================= fallback wrappers (original dispatch structure) ==========

__global__ __launch_bounds__(256) void k_split_g(MegaP p) {
    __shared__ __align__(16) float tile[64*68];
    int task = blockIdx.z, bx = blockIdx.x, by = blockIdx.y;
    if (task == 0 && by >= 6) return;
    if (task == 1 && (bx >= 6 || by >= 39)) return;
    if (task == 2 && (bx >= 8 || by >= 6)) return;
    d_split(p, task, bx, by, tile);
}
__global__ __launch_bounds__(256) void k_proj_g(MegaP p) {
    d_proj(p, blockIdx.x, blockIdx.y);
}
__global__ __launch_bounds__(256) void k_geo_g(MegaP p) {
    __shared__ __align__(16) float sg[408];
    d_geo(p, blockIdx.x, sg);
}
__global__ __launch_bounds__(256) void k_zb_g(MegaP p) {
    d_zb(p, blockIdx.x, blockIdx.y);
}
__global__ __launch_bounds__(256) void k_scorefill_g(MegaP p) {
    d_scorefill(p, blockIdx.x, blockIdx.y, blockIdx.z);
}
__global__ __launch_bounds__(256) void k_softmax_g(MegaP p) {
    __shared__ __align__(16) float sm_[40];
    d_softmax(p, blockIdx.x, sm_);
}
__global__ __launch_bounds__(256) void k_az_g(MegaP p) {
    __shared__ __align__(16) float aT[4608];
    d_az(p, blockIdx.x, blockIdx.y, aT);
}
__global__ __launch_bounds__(256) void k_apply_g(MegaP p) {
    __shared__ __align__(16) u16 sB[12288];
    d_apply(p, blockIdx.x, blockIdx.y, blockIdx.z, sB);
}
__global__ __launch_bounds__(256) void k_azfin_g(MegaP p) {
    __shared__ __align__(16) float sz[2048];
    d_azfin(p, blockIdx.x, sz);
}
__global__ __launch_bounds__(256) void k_sout_g(MegaP p) {
    d_sout(p, blockIdx.x, blockIdx.y, blockIdx.z);
}
__global__ __launch_bounds__(256) void k_red_g(MegaP p) {
    d_red(p, blockIdx.x);
}

// ---------------- launch ----------------

extern "C" void kernel_launch(void* const* d_in, const int* in_sizes, int n_in,
                              void* d_out, int out_size, void* d_ws, size_t ws_size,
                              hipStream_t stream) {
    MegaP P;
    P.s     = (const float*)d_in[0];
    P.g     = (const float*)d_in[1];
    P.z     = (const float*)d_in[2];
    P.T     = (const float*)d_in[3];
    P.mask  = (const float*)d_in[4];
    P.W_q   = (const float*)d_in[5];
    P.b_q   = (const float*)d_in[6];
    P.W_kv  = (const float*)d_in[7];
    P.b_kv  = (const float*)d_in[8];
    P.W_qp  = (const float*)d_in[9];
    P.b_qp  = (const float*)d_in[10];
    P.W_kp  = (const float*)d_in[11];
    P.b_kp  = (const float*)d_in[12];
    P.W_vg  = (const float*)d_in[13];
    P.b_vg  = (const float*)d_in[14];
    P.W_mg  = (const float*)d_in[15];
    P.W_b   = (const float*)d_in[16];
    P.b_b   = (const float*)d_in[17];
    P.W_dz  = (const float*)d_in[18];
    P.b_dz  = (const float*)d_in[19];
    P.hw    = (const float*)d_in[20];
    P.sw    = (const float*)d_in[21];
    P.W_out = (const float*)d_in[22];
    P.b_out = (const float*)d_in[23];
    P.W_geo = (const float*)d_in[24];
    P.ws    = (float*)d_ws;
    P.out   = (float*)d_out;

    void* kargs[] = { (void*)&P };
    hipError_t e = hipLaunchCooperativeKernel((const void*)k_mega,
                                              dim3(512), dim3(256), kargs, 0, stream);
    if (e != hipSuccess) {
        (void)hipGetLastError();   // clear sticky error, fall back to 11-dispatch path
        k_split_g<<<dim3(56,39,3),256,0,stream>>>(P);
        k_proj_g<<<dim3(8,56),256,0,stream>>>(P);
        k_geo_g<<<NN,256,0,stream>>>(P);
        k_zb_g<<<dim3(512,4),256,0,stream>>>(P);
        k_scorefill_g<<<dim3(8,8,8),256,0,stream>>>(P);
        k_softmax_g<<<4096,256,0,stream>>>(P);
        k_az_g<<<dim3(512,4),256,0,stream>>>(P);
        k_apply_g<<<dim3(8,4,16),256,0,stream>>>(P);
        k_azfin_g<<<NN,256,0,stream>>>(P);
        k_sout_g<<<dim3(8,6,6),256,0,stream>>>(P);
        k_red_g<<<192,256,0,stream>>>(P);
    }
}

// Round 10
// 392.930 us; speedup vs baseline: 2.3808x; 2.3808x over previous
//
#include <hip/hip_runtime.h>
#include <math.h>

// ---------------- constants ----------------
#define NN 512
#define CSD 384
#define CZD 128
#define HD 8
#define CD 128
#define EPSV 1e-8f
#define INFV 100000.0f

// ---------------- ws float offsets (no unions; ws is 512 MiB, we use ~52 MB) ----
#define OFF_QN    ((size_t)0)         // 2048
#define OFF_TR    ((size_t)2048)      // 1536
#define OFF_ROWT  ((size_t)4096)      // 4096
#define OFF_COLT  ((size_t)8192)      // 4096
#define OFF_SB    ((size_t)12288)     // 32768
#define OFF_QBUF  ((size_t)45056)     // 524288
#define OFF_KV    ((size_t)569344)    // 1048576
#define OFF_QPR   ((size_t)1617920)   // 98304
#define OFF_KPR   ((size_t)1716224)   // 98304
#define OFF_VGR   ((size_t)1814528)   // 65536
#define OFF_ZB    ((size_t)1880064)   // 2097152
#define OFF_A     ((size_t)3977216)   // 2097152
#define OFF_U     ((size_t)6074368)   // 655360
#define OFF_V     ((size_t)6729728)   // 655360 (stored [h][i][160], row-major)
#define OFF_VP    ((size_t)7385088)   // 1048576
#define OFF_OB0   ((size_t)8433664)   // 524288
#define OFF_OB1   ((size_t)8957952)   // 524288
#define OFF_OG0   ((size_t)9482240)   // 524288
#define OFF_OG1   ((size_t)10006528)  // 524288
#define OFF_FEATS ((size_t)10530816)  // 1277952
#define OFF_PS    ((size_t)11808768)  // 1179648 (6 x 512 x 384)

typedef __attribute__((ext_vector_type(4))) float f32x4;
typedef __attribute__((ext_vector_type(8))) short bf16x8;
typedef __attribute__((ext_vector_type(4))) short s16x4;

__device__ __forceinline__ void qrot(const float q[4], const float* v, float* out) {
    float qw = q[0], qx = q[1], qy = q[2], qz = q[3];
    float ux = qy*v[2] - qz*v[1];
    float uy = qz*v[0] - qx*v[2];
    float uz = qx*v[1] - qy*v[0];
    float uux = qy*uz - qz*uy;
    float uuy = qz*ux - qx*uz;
    float uuz = qx*uy - qy*ux;
    out[0] = v[0] + 2.0f*(qw*ux + uux);
    out[1] = v[1] + 2.0f*(qw*uy + uuy);
    out[2] = v[2] + 2.0f*(qw*uz + uuz);
}

// fp32 -> bf16 (RNE) hi + residual lo
__device__ __forceinline__ void cvt2(float x, unsigned short& h, unsigned short& lo) {
    unsigned u = __float_as_uint(x);
    unsigned r = (u + 0x7FFFu + ((u >> 16) & 1u)) >> 16;
    h = (unsigned short)r;
    float hf = __uint_as_float(r << 16);
    float lf = x - hf;
    unsigned u2 = __float_as_uint(lf);
    unsigned r2 = (u2 + 0x7FFFu + ((u2 >> 16) & 1u)) >> 16;
    lo = (unsigned short)r2;
}

// store 4 consecutive k for one row (row-major staging), stride 40 shorts
__device__ __forceinline__ void stA(short* H, short* L, int row, int k4, float4 v) {
    unsigned short h0,l0,h1,l1,h2,l2,h3,l3;
    cvt2(v.x,h0,l0); cvt2(v.y,h1,l1); cvt2(v.z,h2,l2); cvt2(v.w,h3,l3);
    s16x4 vh = {(short)h0,(short)h1,(short)h2,(short)h3};
    s16x4 vl = {(short)l0,(short)l1,(short)l2,(short)l3};
    *(s16x4*)(H + row*40 + k4) = vh;
    *(s16x4*)(L + row*40 + k4) = vl;
}
// transposed staging: 4 consecutive n for one k
__device__ __forceinline__ void stBT(short* H, short* L, int k, int n4, float4 v) {
    unsigned short h, lo;
    cvt2(v.x,h,lo); H[(n4+0)*40+k]=(short)h; L[(n4+0)*40+k]=(short)lo;
    cvt2(v.y,h,lo); H[(n4+1)*40+k]=(short)h; L[(n4+1)*40+k]=(short)lo;
    cvt2(v.z,h,lo); H[(n4+2)*40+k]=(short)h; L[(n4+2)*40+k]=(short)lo;
    cvt2(v.w,h,lo); H[(n4+3)*40+k]=(short)h; L[(n4+3)*40+k]=(short)lo;
}

// ---------- MFMA tile core: 64x64 tile, K-step 32, 256 thr (4 waves) ----------
template<int BT>
__device__ __forceinline__ void mfma_tiles(const float* __restrict__ A, int lda,
                                           const float* __restrict__ B, int ldb,
                                           int m0, int n0, int k0, int nk,
                                           f32x4* acc,
                                           short* Ah, short* Al, short* Bh, short* Bl) {
    int t = threadIdx.x;
    int w = t >> 6, l = t & 63, g = l >> 4, li = l & 15;
    int ar = t >> 3, ak = (t & 7) << 2;
    const float* Ap0 = A + (size_t)(m0 + ar)*lda + ak;
    const float* Ap1 = A + (size_t)(m0 + ar + 32)*lda + ak;
    const float* Bp0; const float* Bp1;
    int bk = t >> 4, bn = (t & 15) << 2;
    if (BT) {
        Bp0 = B + (size_t)(n0 + ar)*ldb + ak;
        Bp1 = B + (size_t)(n0 + ar + 32)*ldb + ak;
    } else {
        Bp0 = B + (size_t)bk*ldb + n0 + bn;
        Bp1 = B + (size_t)(bk + 16)*ldb + n0 + bn;
    }
    float4 a0 = *(const float4*)(Ap0 + k0);
    float4 a1 = *(const float4*)(Ap1 + k0);
    float4 b0, b1;
    if (BT) { b0 = *(const float4*)(Bp0 + k0); b1 = *(const float4*)(Bp1 + k0); }
    else    { b0 = *(const float4*)(Bp0 + (size_t)k0*ldb); b1 = *(const float4*)(Bp1 + (size_t)k0*ldb); }
    for (int kc = 0; kc < nk; kc++) {
        stA(Ah, Al, ar, ak, a0);
        stA(Ah, Al, ar+32, ak, a1);
        if (BT) { stA(Bh, Bl, ar, ak, b0); stA(Bh, Bl, ar+32, ak, b1); }
        else    { stBT(Bh, Bl, bk, bn, b0); stBT(Bh, Bl, bk+16, bn, b1); }
        __syncthreads();
        if (kc + 1 < nk) {
            int kb = k0 + (kc+1)*32;
            a0 = *(const float4*)(Ap0 + kb);
            a1 = *(const float4*)(Ap1 + kb);
            if (BT) { b0 = *(const float4*)(Bp0 + kb); b1 = *(const float4*)(Bp1 + kb); }
            else { b0 = *(const float4*)(Bp0 + (size_t)kb*ldb); b1 = *(const float4*)(Bp1 + (size_t)kb*ldb); }
        }
        int arow = (w*16 + li)*40 + g*8;
        bf16x8 avh = *(bf16x8*)(Ah + arow);
        bf16x8 avl = *(bf16x8*)(Al + arow);
        #pragma unroll
        for (int c = 0; c < 4; c++) {
            int brow = (c*16 + li)*40 + g*8;
            bf16x8 bvh = *(bf16x8*)(Bh + brow);
            bf16x8 bvl = *(bf16x8*)(Bl + brow);
            acc[c] = __builtin_amdgcn_mfma_f32_16x16x32_bf16(avh, bvh, acc[c], 0, 0, 0);
            acc[c] = __builtin_amdgcn_mfma_f32_16x16x32_bf16(avh, bvl, acc[c], 0, 0, 0);
            acc[c] = __builtin_amdgcn_mfma_f32_16x16x32_bf16(avl, bvh, acc[c], 0, 0, 0);
        }
        __syncthreads();
    }
}

// ---------- VALU tiled-GEMM core (k_proj_all / k_sout) ----------
__device__ __forceinline__ void gemm_tiles(const float* __restrict__ A, int lda,
                                           const float* __restrict__ B, int ldb,
                                           int m0, int n0, int k0, int nk,
                                           float acc[4][4], float* AsT, float* Bs) {
    int t = threadIdx.x;
    int tx = t & 15, ty = t >> 4;
    int arow = t >> 3, ak4 = (t & 7) << 2;
    int brow = t >> 4, bc4 = (t & 15) << 2;
    const float* Ap0 = A + (size_t)(m0 + arow)*lda + ak4;
    const float* Ap1 = A + (size_t)(m0 + arow + 32)*lda + ak4;
    const float* Bp0 = B + (size_t)brow*ldb + n0 + bc4;
    const float* Bp1 = B + (size_t)(brow + 16)*ldb + n0 + bc4;
    float4 a0 = *(const float4*)(Ap0 + k0);
    float4 a1 = *(const float4*)(Ap1 + k0);
    float4 b0 = *(const float4*)(Bp0 + (size_t)k0*ldb);
    float4 b1 = *(const float4*)(Bp1 + (size_t)k0*ldb);
    for (int kc = 0; kc < nk; kc++) {
        AsT[(ak4+0)*68 + arow] = a0.x;
        AsT[(ak4+1)*68 + arow] = a0.y;
        AsT[(ak4+2)*68 + arow] = a0.z;
        AsT[(ak4+3)*68 + arow] = a0.w;
        AsT[(ak4+0)*68 + arow+32] = a1.x;
        AsT[(ak4+1)*68 + arow+32] = a1.y;
        AsT[(ak4+2)*68 + arow+32] = a1.z;
        AsT[(ak4+3)*68 + arow+32] = a1.w;
        *(float4*)(Bs + brow*64 + bc4) = b0;
        *(float4*)(Bs + (brow+16)*64 + bc4) = b1;
        __syncthreads();
        if (kc + 1 < nk) {
            int kb = k0 + (kc+1)*32;
            a0 = *(const float4*)(Ap0 + kb);
            a1 = *(const float4*)(Ap1 + kb);
            b0 = *(const float4*)(Bp0 + (size_t)kb*ldb);
            b1 = *(const float4*)(Bp1 + (size_t)kb*ldb);
        }
        #pragma unroll
        for (int kk = 0; kk < 32; kk++) {
            float4 av = *(const float4*)(AsT + kk*68 + ty*4);
            float4 bv = *(const float4*)(Bs + kk*64 + tx*4);
            acc[0][0] += av.x*bv.x; acc[0][1] += av.x*bv.y; acc[0][2] += av.x*bv.z; acc[0][3] += av.x*bv.w;
            acc[1][0] += av.y*bv.x; acc[1][1] += av.y*bv.y; acc[1][2] += av.y*bv.z; acc[1][3] += av.y*bv.w;
            acc[2][0] += av.z*bv.x; acc[2][1] += av.z*bv.y; acc[2][2] += av.z*bv.z; acc[2][3] += av.z*bv.w;
            acc[3][0] += av.w*bv.x; acc[3][1] += av.w*bv.y; acc[3][2] += av.w*bv.z; acc[3][3] += av.w*bv.w;
        }
        __syncthreads();
    }
}

// ---------------- kernels ----------------

__global__ __launch_bounds__(256) void k_proj_all(const float* __restrict__ s,
    const float* __restrict__ W_q,  const float* __restrict__ b_q,  float* __restrict__ qbuf,
    const float* __restrict__ W_kv, const float* __restrict__ b_kv, float* __restrict__ kvb,
    const float* __restrict__ W_qp, const float* __restrict__ b_qp, float* __restrict__ qpr,
    const float* __restrict__ W_kp, const float* __restrict__ b_kp, float* __restrict__ kpr,
    const float* __restrict__ W_vg, const float* __restrict__ b_vg, float* __restrict__ vgr) {
    __shared__ float AsT[32*68];
    __shared__ float Bs[32*64];
    int ny = blockIdx.y;
    const float* W; const float* bias; float* C; int N; int n0;
    if (ny < 16)      { W=W_q;  bias=b_q;  C=qbuf; N=1024; n0=ny*64; }
    else if (ny < 48) { W=W_kv; bias=b_kv; C=kvb;  N=2048; n0=(ny-16)*64; }
    else if (ny < 51) { W=W_qp; bias=b_qp; C=qpr;  N=192;  n0=(ny-48)*64; }
    else if (ny < 54) { W=W_kp; bias=b_kp; C=kpr;  N=192;  n0=(ny-51)*64; }
    else              { W=W_vg; bias=b_vg; C=vgr;  N=128;  n0=(ny-54)*64; }
    int m0 = blockIdx.x*64;
    float acc[4][4] = {};
    gemm_tiles(s, CSD, W, N, m0, n0, 0, 12, acc, AsT, Bs);
    int tx = threadIdx.x & 15, ty = threadIdx.x >> 4;
    float4 bb = *(const float4*)(bias + n0 + tx*4);
    #pragma unroll
    for (int rr = 0; rr < 4; rr++) {
        float4 o = make_float4(acc[rr][0]+bb.x, acc[rr][1]+bb.y, acc[rr][2]+bb.z, acc[rr][3]+bb.w);
        *(float4*)(C + (size_t)(m0+ty*4+rr)*N + n0 + tx*4) = o;
    }
}

// fused: prep + q-points + k-points + vg + uv + Vp-pack. One block per residue n.
__global__ __launch_bounds__(256) void k_geo(
    const float* __restrict__ T,
    const float* __restrict__ qpr, const float* __restrict__ kpr,
    const float* __restrict__ vgr, const float* __restrict__ g,
    const float* __restrict__ W_mg,
    const float* __restrict__ qbuf, const float* __restrict__ kvb,
    const float* __restrict__ hwraw, const float* __restrict__ b_b,
    float* __restrict__ qn, float* __restrict__ tr,
    float* __restrict__ U, float* __restrict__ V,
    float* __restrict__ rowt, float* __restrict__ colt,
    float* __restrict__ Vp)
{
    __shared__ float s_q[4];
    __shared__ float s_t[3];
    __shared__ float s_qpts[192], s_kpts[192];
    __shared__ float s_Qsq[8], s_Ksq[8];
    int n = blockIdx.x, t = threadIdx.x;
    if (t == 0) {
        float q0=T[n*16+0], q1=T[n*16+1], q2=T[n*16+2], q3=T[n*16+3];
        float inv = 1.0f/sqrtf(q0*q0+q1*q1+q2*q2+q3*q3 + EPSV);
        float a0=q0*inv, a1=q1*inv, a2=q2*inv, a3=q3*inv;
        s_q[0]=a0; s_q[1]=a1; s_q[2]=a2; s_q[3]=a3;
        float u0=T[n*16+4], u1=T[n*16+5], u2=T[n*16+6];
        s_t[0]=u0; s_t[1]=u1; s_t[2]=u2;
        qn[n*4+0]=a0; qn[n*4+1]=a1; qn[n*4+2]=a2; qn[n*4+3]=a3;
        tr[n*3+0]=u0; tr[n*3+1]=u1; tr[n*3+2]=u2;
    }
    __syncthreads();
    float q[4]={s_q[0],s_q[1],s_q[2],s_q[3]};
    float t0=s_t[0], t1=s_t[1], t2=s_t[2];
    if (t < 128) {
        int m = t & 63;
        const float* raw = (t < 64) ? qpr : kpr;
        float p[3] = {raw[n*192 + m], raw[n*192 + 64 + m], raw[n*192 + 128 + m]};
        float r[3]; qrot(q,p,r);
        r[0]+=t0; r[1]+=t1; r[2]+=t2;
        float* dp = (t<64) ? s_qpts : s_kpts;
        dp[m*3+0]=r[0]; dp[m*3+1]=r[1]; dp[m*3+2]=r[2];
        float ss = r[0]*r[0]+r[1]*r[1]+r[2]*r[2];
        ss += __shfl_down(ss,4,8);
        ss += __shfl_down(ss,2,8);
        ss += __shfl_down(ss,1,8);
        if ((m&7)==0) ((t<64)?s_Qsq:s_Ksq)[m>>3] = ss;
    } else if (t < 192) {
        int o = t - 128;
        float in[16];
        #pragma unroll
        for (int c=0;c<16;c++){
            float acc=0.0f;
            #pragma unroll
            for (int i=0;i<8;i++)  acc += W_mg[o*16+i]*vgr[n*128+i*16+c];
            #pragma unroll
            for (int i=8;i<16;i++) acc += W_mg[o*16+i]*g[n*128+(i-8)*16+c];
            in[c]=acc;
        }
        float out[16];
        out[0]=in[0];
        qrot(q,in+1,out+1);
        qrot(q,in+4,out+4);
        float w=in[10];
        qrot(q,in+7,out+7);
        out[7]+=w*t0; out[8]+=w*t1; out[9]+=w*t2;
        #pragma unroll
        for (int c=10;c<16;c++) out[c]=in[c];
        int h=o>>3, pp=o&7;
        float* vp = Vp + ((size_t)(h*512+n))*256 + 128 + pp*16;
        #pragma unroll
        for (int c=0;c<16;c++) vp[c]=out[c];
    }
    #pragma unroll
    for (int l=0;l<4;l++){
        int f = t + l*256; int h = f>>7, c = f&127;
        Vp[((size_t)(h*512+n))*256 + c] = kvb[(size_t)n*2048 + h*256 + 128 + c];
    }
    __syncthreads();
    #pragma unroll
    for (int h = 0; h < 8; h++) {
        float hwv = log1pf(expf(hwraw[h])) * 0.09622504486493763f; // softplus * sqrt(1/108)
        if (t < 160) {
            float u, v;
            if (t < 128) {
                u = 0.05103103630798287f * qbuf[(size_t)n*1024 + h*128 + t]; // sqrt(1/384)
                v = kvb[(size_t)n*2048 + h*256 + t];
            } else if (t < 152) {
                int d = t - 128;
                u = hwv * s_qpts[h*24 + d];
                v = s_kpts[h*24 + d];
            } else { u = 0.0f; v = 0.0f; }
            U[((size_t)h*512 + n)*160 + t] = u;
            V[((size_t)h*512 + n)*160 + t] = v;   // row-major
        }
        if (t == 160) rowt[h*512+n] = -0.5f*hwv*s_Qsq[h] + 0.5773502691896258f*b_b[h] - INFV;
        if (t == 161) colt[h*512+n] = -0.5f*hwv*s_Ksq[h];
    }
}

// zb[h][i][j] = sum_c z[i,j,c] * W_b[c,h]
// v3: 16-lane group per j-row, weights in registers, 32B/lane coalesced reads,
// no LDS, grid (512,4)x256. SINGLE-VARIABLE change vs the 402us config.
__global__ __launch_bounds__(256) void k_zb(const float* __restrict__ z,
        const float* __restrict__ W_b, float* __restrict__ zb) {
    int i = blockIdx.x, j0 = blockIdx.y*128;
    int t = threadIdx.x, w = t>>6, l = t&63;
    int gp = l>>4, k = l&15;
    float wb[8][8];
    #pragma unroll
    for (int cc=0;cc<8;cc++){
        float4 w0 = *(const float4*)(W_b + (k*8+cc)*8);
        float4 w1 = *(const float4*)(W_b + (k*8+cc)*8 + 4);
        wb[cc][0]=w0.x; wb[cc][1]=w0.y; wb[cc][2]=w0.z; wb[cc][3]=w0.w;
        wb[cc][4]=w1.x; wb[cc][5]=w1.y; wb[cc][6]=w1.z; wb[cc][7]=w1.w;
    }
    for (int it = 0; it < 8; it++) {
        int j = j0 + it*16 + w*4 + gp;
        const float* zp = z + ((size_t)i*512 + j)*128 + k*8;
        float4 za = *(const float4*)(zp);
        float4 zb4 = *(const float4*)(zp + 4);
        float zz[8] = {za.x,za.y,za.z,za.w,zb4.x,zb4.y,zb4.z,zb4.w};
        float acc[8];
        #pragma unroll
        for (int h=0;h<8;h++) acc[h] = zz[0]*wb[0][h];
        #pragma unroll
        for (int cc=1;cc<8;cc++)
            #pragma unroll
            for (int h=0;h<8;h++) acc[h] += zz[cc]*wb[cc][h];
        #pragma unroll
        for (int h=0;h<8;h++) {
            acc[h] += __shfl_xor(acc[h], 1);
            acc[h] += __shfl_xor(acc[h], 2);
            acc[h] += __shfl_xor(acc[h], 4);
            acc[h] += __shfl_xor(acc[h], 8);
        }
        float outv = acc[0];
        #pragma unroll
        for (int h=1;h<8;h++) if (k == h) outv = acc[h];
        if (k < 8) zb[((size_t)k*512 + i)*512 + j] = outv;
    }
}

// raw scores via K=160 MFMA GEMM + affine epilogue
__global__ __launch_bounds__(256) void k_scorefill(const float* __restrict__ U, const float* __restrict__ V,
        const float* __restrict__ rowt, const float* __restrict__ colt,
        const float* __restrict__ zb, const float* __restrict__ mask,
        const float* __restrict__ sw, float* __restrict__ Am) {
    __shared__ short Ah[64*40], Al[64*40], Bh[64*40], Bl[64*40];
    int h = blockIdx.z;
    int m0 = blockIdx.x*64, n0 = blockIdx.y*64;
    f32x4 acc[4] = {};
    mfma_tiles<1>(U + (size_t)h*512*160, 160, V + (size_t)h*512*160, 160,
                  m0, n0, 0, 5, acc, Ah, Al, Bh, Bl);
    int t = threadIdx.x, w = t >> 6, l = t & 63, g = l >> 4, li = l & 15;
    float swh = sw[h];
    #pragma unroll
    for (int c = 0; c < 4; c++) {
        int j = n0 + c*16 + li;
        float ct = colt[h*512 + j];
        float mj = mask[j];
        #pragma unroll
        for (int r = 0; r < 4; r++) {
            int i = m0 + w*16 + g*4 + r;
            float rt = rowt[h*512 + i];
            float mi = mask[i]*INFV;
            float zv = zb[((size_t)h*512 + i)*512 + j];
            Am[((size_t)h*512 + i)*512 + j] =
                (acc[c][r] + rt + ct + 0.5773502691896258f*zv + mi*mj)*swh;
        }
    }
}

// softmax over each (h,i) row, in-place; fuses the S-moments (o_rel reduction)
__global__ __launch_bounds__(256) void k_softmax(float* __restrict__ Am,
        const float* __restrict__ qn, const float* __restrict__ tr, float* __restrict__ S) {
    __shared__ float red[8];
    __shared__ float sred[4][8];
    int row = blockIdx.x;           // h*512 + i
    float* p = Am + (size_t)row*512;
    int t = threadIdx.x;            // 256
    float x0 = p[t], x1 = p[t+256];
    float m = fmaxf(x0, x1);
    #pragma unroll
    for (int o = 32; o > 0; o >>= 1) m = fmaxf(m, __shfl_xor(m, o));
    int wv = t >> 6, ln = t & 63;
    if (ln == 0) red[wv] = m;
    __syncthreads();
    m = fmaxf(fmaxf(red[0], red[1]), fmaxf(red[2], red[3]));
    float e0 = expf(x0 - m), e1 = expf(x1 - m);
    float sm = e0 + e1;
    #pragma unroll
    for (int o = 32; o > 0; o >>= 1) sm += __shfl_xor(sm, o);
    __syncthreads();
    if (ln == 0) red[4 + wv] = sm;
    __syncthreads();
    float inv = 1.0f / (red[4]+red[5]+red[6]+red[7]);
    float a0 = e0*inv, a1 = e1*inv;
    p[t] = a0;
    p[t+256] = a1;
    float4 q0 = *(const float4*)(qn + t*4);
    float4 q1 = *(const float4*)(qn + (t+256)*4);
    float acc[8];
    acc[0] = a0*q0.x + a1*q1.x;
    acc[1] = a0*q0.y + a1*q1.y;
    acc[2] = a0*q0.z + a1*q1.z;
    acc[3] = a0*q0.w + a1*q1.w;
    acc[4] = a0*tr[t*3+0] + a1*tr[(t+256)*3+0];
    acc[5] = a0*tr[t*3+1] + a1*tr[(t+256)*3+1];
    acc[6] = a0*tr[t*3+2] + a1*tr[(t+256)*3+2];
    acc[7] = a0 + a1;
    #pragma unroll
    for (int c = 0; c < 8; c++) {
        #pragma unroll
        for (int o = 32; o > 0; o >>= 1) acc[c] += __shfl_xor(acc[c], o);
    }
    if (ln == 0) {
        #pragma unroll
        for (int c = 0; c < 8; c++) sred[wv][c] = acc[c];
    }
    __syncthreads();
    if (t < 8) {
        int h = row >> 9, i = row & 511;
        S[i*64 + h*8 + t] = sred[0][t]+sred[1][t]+sred[2][t]+sred[3][t];
    }
}

// o and o_g via MFMA GEMM: per js in {0,1}, non-atomic stores into separate slabs.
__global__ __launch_bounds__(256) void k_apply(const float* __restrict__ Am,
        const float* __restrict__ Vp, float* __restrict__ ob0, float* __restrict__ ob1,
        float* __restrict__ og0, float* __restrict__ og1) {
    __shared__ short Ah[64*40], Al[64*40], Bh[64*40], Bl[64*40];
    int m0 = blockIdx.x*64;             // i tile
    int n0 = blockIdx.y*64;             // col tile (0..255)
    int h = blockIdx.z & 7, js = blockIdx.z >> 3;
    f32x4 acc[4] = {};
    mfma_tiles<0>(Am + (size_t)h*512*512, 512, Vp + (size_t)h*512*256, 256,
                  m0, n0, js*256, 8, acc, Ah, Al, Bh, Bl);
    int t = threadIdx.x, w = t >> 6, l = t & 63, g = l >> 4, li = l & 15;
    float* obuf = js ? ob1 : ob0;
    float* og   = js ? og1 : og0;
    #pragma unroll
    for (int c = 0; c < 4; c++) {
        int col = n0 + c*16 + li;
        float* base = (col < 128) ? (obuf + h*128 + col) : (og + h*128 + col - 128);
        #pragma unroll
        for (int r = 0; r < 4; r++) {
            int i = m0 + w*16 + g*4 + r;
            base[(size_t)i*1024] = acc[c][r];
        }
    }
}

// fused: az (in LDS) + finalize + gout. One block per residue i, 256 threads.
__global__ __launch_bounds__(256) void k_azfin(
    const float* __restrict__ Am, const float* __restrict__ z,
    const float* __restrict__ ob0, const float* __restrict__ ob1,
    const float* __restrict__ og0, const float* __restrict__ og1,
    const float* __restrict__ W_dz, const float* __restrict__ b_dz,
    const float* __restrict__ S, const float* __restrict__ qn, const float* __restrict__ tr,
    const float* __restrict__ W_geo,
    float* __restrict__ feats, float* __restrict__ outg)
{
    __shared__ float aT[512*8];     // [j][h]
    __shared__ float part[3*1024];
    __shared__ float s_az[1024];    // [h][128]
    __shared__ float s_og[1024];    // [(h*8+p)][16], post-transform
    int i = blockIdx.x, t = threadIdx.x;
    #pragma unroll
    for (int l = 0; l < 16; l++) {
        int f = t + l*256;
        int h = f >> 9, j = f & 511;
        aT[j*8 + h] = Am[((size_t)h*512 + i)*512 + j];
    }
    __syncthreads();
    int c2 = t & 63, quarter = t >> 6;
    int jb = quarter*128;
    float acc[8][2] = {};
    for (int j = jb; j < jb+128; j++) {
        float2 zv = *(const float2*)(z + ((size_t)(i*NN) + j)*CZD + c2*2);
        float4 a0 = *(const float4*)(aT + j*8);
        float4 a1 = *(const float4*)(aT + j*8 + 4);
        acc[0][0] += a0.x*zv.x; acc[0][1] += a0.x*zv.y;
        acc[1][0] += a0.y*zv.x; acc[1][1] += a0.y*zv.y;
        acc[2][0] += a0.z*zv.x; acc[2][1] += a0.z*zv.y;
        acc[3][0] += a0.w*zv.x; acc[3][1] += a0.w*zv.y;
        acc[4][0] += a1.x*zv.x; acc[4][1] += a1.x*zv.y;
        acc[5][0] += a1.y*zv.x; acc[5][1] += a1.y*zv.y;
        acc[6][0] += a1.z*zv.x; acc[6][1] += a1.z*zv.y;
        acc[7][0] += a1.w*zv.x; acc[7][1] += a1.w*zv.y;
    }
    if (quarter > 0) {
        #pragma unroll
        for (int h = 0; h < 8; h++) {
            part[(quarter-1)*1024 + h*128 + c2*2 + 0] = acc[h][0];
            part[(quarter-1)*1024 + h*128 + c2*2 + 1] = acc[h][1];
        }
    }
    __syncthreads();
    if (quarter == 0) {
        #pragma unroll
        for (int h = 0; h < 8; h++) {
            #pragma unroll
            for (int d = 0; d < 2; d++) {
                s_az[h*128 + c2*2 + d] = acc[h][d] + part[h*128 + c2*2 + d]
                          + part[1024 + h*128 + c2*2 + d] + part[2048 + h*128 + c2*2 + d];
            }
        }
    }
    __syncthreads();
    float* f = feats + (size_t)i*2496;
    #pragma unroll
    for (int l = 0; l < 4; l++) {
        int ff = t + l*256; int h = ff>>7, c = ff&127;
        f[h*312 + 32 + c] = ob0[(size_t)i*1024 + h*128 + c] + ob1[(size_t)i*1024 + h*128 + c];
    }
    {
        int h = t >> 5, cdz = t & 31;
        float a2 = b_dz[cdz];
        #pragma unroll 4
        for (int zc = 0; zc < 128; zc++) a2 += s_az[h*128 + zc]*W_dz[zc*32 + cdz];
        f[h*312 + cdz] = a2;
    }
    float qc0=qn[i*4], qc1=-qn[i*4+1], qc2=-qn[i*4+2], qc3=-qn[i*4+3];
    float t0=tr[i*3], t1=tr[i*3+1], t2=tr[i*3+2];
    if (t < 64) {
        int h = t >> 3, p = t & 7;
        const float* a0 = og0 + (size_t)i*1024 + h*128 + p*16;
        const float* a1 = og1 + (size_t)i*1024 + h*128 + p*16;
        float in[16];
        #pragma unroll
        for (int c=0;c<16;c++) in[c]=a0[c]+a1[c];
        float qc[4]={qc0,qc1,qc2,qc3};
        float out[16];
        out[0]=in[0];
        qrot(qc,in+1,out+1);
        qrot(qc,in+4,out+4);
        float w=in[10];
        float tmp[3]={in[7]-w*t0, in[8]-w*t1, in[9]-w*t2};
        qrot(qc,tmp,out+7);
        #pragma unroll
        for (int c2x=10;c2x<16;c2x++) out[c2x]=in[c2x];
        float n1=EPSV, n2=EPSV;
        #pragma unroll
        for (int c2x=0;c2x<10;c2x++) n1 += out[c2x]*out[c2x];
        #pragma unroll
        for (int c2x=10;c2x<16;c2x++) n2 += out[c2x]*out[c2x];
        n1=sqrtf(n1); n2=sqrtf(n2);
        #pragma unroll
        for (int c2x=0;c2x<16;c2x++){ f[h*312+168+p*16+c2x]=out[c2x]; s_og[t*16+c2x]=out[c2x]; }
        f[h*312+296+p*2]=n1; f[h*312+296+p*2+1]=n2;
    } else if (t < 72) {
        int h = t - 64;
        const float* Sr = S + i*64 + h*8;
        float b0=Sr[0], b1=Sr[1], b2=Sr[2], b3=Sr[3];
        f[h*312+160] = qc0*b0 - qc1*b1 - qc2*b2 - qc3*b3;
        f[h*312+161] = qc0*b1 + qc1*b0 + qc2*b3 - qc3*b2;
        f[h*312+162] = qc0*b2 - qc1*b3 + qc2*b0 + qc3*b1;
        f[h*312+163] = qc0*b3 + qc1*b2 - qc2*b1 + qc3*b0;
        float A = Sr[7];
        float v[3]={Sr[4]-A*t0, Sr[5]-A*t1, Sr[6]-A*t2};
        float qc[4]={qc0,qc1,qc2,qc3};
        float r[3]; qrot(qc,v,r);
        f[h*312+164]=r[0]; f[h*312+165]=r[1]; f[h*312+166]=r[2]; f[h*312+167]=0.0f;
    }
    __syncthreads();
    if (t < 128) {
        int o = (t>>4) & 7, c = t & 15;
        float a3 = 0.0f;
        #pragma unroll 4
        for (int i2=0;i2<64;i2++) a3 += W_geo[o*64+i2]*s_og[i2*16+c];
        outg[(size_t)i*128 + o*16 + c] = a3;
    }
}

// s_out: split-K tiled GEMM into 6 non-atomic slabs
__global__ __launch_bounds__(256) void k_sout(const float* __restrict__ feats,
        const float* __restrict__ W_out, float* __restrict__ Ps) {
    __shared__ float AsT[32*68];
    __shared__ float Bs[32*64];
    int m0 = blockIdx.x*64, n0 = blockIdx.y*64, kz = blockIdx.z;
    float acc[4][4] = {};
    gemm_tiles(feats, 2496, W_out, CSD, m0, n0, kz*416, 13, acc, AsT, Bs);
    int tx = threadIdx.x & 15, ty = threadIdx.x >> 4;
    float* slab = Ps + (size_t)kz*512*384;
    #pragma unroll
    for (int rr = 0; rr < 4; rr++) {
        *(float4*)(slab + (size_t)(m0+ty*4+rr)*CSD + n0 + tx*4) =
            make_float4(acc[rr][0], acc[rr][1], acc[rr][2], acc[rr][3]);
    }
}

// reduce the 6 slabs + bias -> out
__global__ __launch_bounds__(256) void k_sout_red(const float* __restrict__ Ps,
        const float* __restrict__ b_out, float* __restrict__ out) {
    int idx = (blockIdx.x*256 + threadIdx.x)*4;   // 196608 floats total
    float4 s = *(const float4*)(b_out + (idx % 384));
    #pragma unroll
    for (int kz = 0; kz < 6; kz++) {
        float4 p = *(const float4*)(Ps + (size_t)kz*196608 + idx);
        s.x += p.x; s.y += p.y; s.z += p.z; s.w += p.w;
    }
    *(float4*)(out + idx) = s;
}

// ---------------- launch ----------------

extern "C" void kernel_launch(void* const* d_in, const int* in_sizes, int n_in,
                              void* d_out, int out_size, void* d_ws, size_t ws_size,
                              hipStream_t stream) {
    const float* s     = (const float*)d_in[0];
    const float* g     = (const float*)d_in[1];
    const float* z     = (const float*)d_in[2];
    const float* T     = (const float*)d_in[3];
    const float* mask  = (const float*)d_in[4];
    const float* W_q   = (const float*)d_in[5];
    const float* b_q   = (const float*)d_in[6];
    const float* W_kv  = (const float*)d_in[7];
    const float* b_kv  = (const float*)d_in[8];
    const float* W_qp  = (const float*)d_in[9];
    const float* b_qp  = (const float*)d_in[10];
    const float* W_kp  = (const float*)d_in[11];
    const float* b_kp  = (const float*)d_in[12];
    const float* W_vg  = (const float*)d_in[13];
    const float* b_vg  = (const float*)d_in[14];
    const float* W_mg  = (const float*)d_in[15];
    const float* W_b   = (const float*)d_in[16];
    const float* b_b   = (const float*)d_in[17];
    const float* W_dz  = (const float*)d_in[18];
    const float* b_dz  = (const float*)d_in[19];
    const float* hw    = (const float*)d_in[20];
    const float* sw    = (const float*)d_in[21];
    const float* W_out = (const float*)d_in[22];
    const float* b_out = (const float*)d_in[23];
    const float* W_geo = (const float*)d_in[24];

    float* ws   = (float*)d_ws;
    float* out  = (float*)d_out;

    float* qn   = ws + OFF_QN;
    float* tr   = ws + OFF_TR;
    float* rowt = ws + OFF_ROWT;
    float* colt = ws + OFF_COLT;
    float* Sbuf = ws + OFF_SB;
    float* qbuf = ws + OFF_QBUF;
    float* kvb  = ws + OFF_KV;
    float* qpr  = ws + OFF_QPR;
    float* kpr  = ws + OFF_KPR;
    float* vgr  = ws + OFF_VGR;
    float* zb   = ws + OFF_ZB;
    float* Am   = ws + OFF_A;
    float* U    = ws + OFF_U;
    float* V    = ws + OFF_V;
    float* Vp   = ws + OFF_VP;
    float* ob0  = ws + OFF_OB0;
    float* ob1  = ws + OFF_OB1;
    float* og0  = ws + OFF_OG0;
    float* og1  = ws + OFF_OG1;
    float* feats= ws + OFF_FEATS;
    float* Ps   = ws + OFF_PS;

    k_proj_all<<<dim3(8,56),256,0,stream>>>(s, W_q,b_q,qbuf, W_kv,b_kv,kvb,
                                            W_qp,b_qp,qpr, W_kp,b_kp,kpr, W_vg,b_vg,vgr);
    k_geo<<<NN,256,0,stream>>>(T,qpr,kpr,vgr,g,W_mg,qbuf,kvb,hw,b_b,
                               qn,tr,U,V,rowt,colt,Vp);
    k_zb<<<dim3(512,4),256,0,stream>>>(z,W_b,zb);
    k_scorefill<<<dim3(8,8,8),256,0,stream>>>(U,V,rowt,colt,zb,mask,sw,Am);
    k_softmax<<<4096,256,0,stream>>>(Am,qn,tr,Sbuf);
    k_apply<<<dim3(8,4,16),256,0,stream>>>(Am,Vp,ob0,ob1,og0,og1);
    k_azfin<<<NN,256,0,stream>>>(Am,z,ob0,ob1,og0,og1,W_dz,b_dz,Sbuf,qn,tr,W_geo,
                                 feats, out + (size_t)NN*CSD);
    k_sout<<<dim3(8,6,6),256,0,stream>>>(feats,W_out,Ps);
    k_sout_red<<<192,256,0,stream>>>(Ps,b_out,out);
}